// Round 2
// 144.491 us; speedup vs baseline: 1.0104x; 1.0104x over previous
//
#include <hip/hip_runtime.h>

// Problem constants
#define B_SZ 2048
#define NB   2000
#define DB   30
#define KK   20
#define LL   40
#define PP   2

// Blob per (k,p,l) [stride 336 floats], order [k][p][l]:
//   0: W1[16] f32 | 16: b1[16] f32 | 32: b2[16] f32
//  48: b3p[16] f32 (j'>=8 -> 0) | 64: W4f[16] f32 (W4*sigmoid(alpha), j'>=8 -> 0)
//  80: W2A 256 f16 A-frag | 208: W3A 256 f16 A-frag (rows j'>=8 zero)
#define BLOB_F 336

typedef _Float16 f16x4 __attribute__((ext_vector_type(4)));
typedef _Float16 f16x2 __attribute__((ext_vector_type(2)));
typedef float    f32x4 __attribute__((ext_vector_type(4)));

union F16x4 { f16x4 v; f16x2 h[2]; };

__device__ __forceinline__ float sigmoidf_fast(float z) {
    return 1.0f / (1.0f + __expf(-z));
}
__device__ __forceinline__ float eluf(float x) {
    return x > 0.0f ? x : (__expf(x) - 1.0f);
}
// elu(x) = max(x, exp2(min(x,0)*log2e) - 1): exp(min(x,0))-1 >= x for x<=0
// (convexity), and = 0 <= x for x>0. Packed v2f16: v_pk_min/mul/add/max +
// 2x v_exp_f16 (llvm.exp2.f16 is legal on gfx950 -> native instruction).
__device__ __forceinline__ f16x2 elu2(f16x2 x) {
    const f16x2 z2  = {(_Float16)0.0f, (_Float16)0.0f};
    const f16x2 l2e = {(_Float16)1.4426950408889634f, (_Float16)1.4426950408889634f};
    const f16x2 m1  = {(_Float16)-1.0f, (_Float16)-1.0f};
    f16x2 e = __builtin_elementwise_exp2(__builtin_elementwise_min(x, z2) * l2e);
    return __builtin_elementwise_max(x, e + m1);
}
__device__ __forceinline__ f16x2 pack2(float a, float b) {
    f16x2 r = {(_Float16)a, (_Float16)b};   // RNE fptrunc, same as old f16 cast
    return r;
}

// K1: w_act only (+ g_T zero). 320 blocks * 256 = 81920 == LL*B_SZ exactly.
__global__ __launch_bounds__(256) void k1_wact(
    const float* __restrict__ locs, const float* __restrict__ mu,
    const float* __restrict__ r,
    float* __restrict__ w_act, float* __restrict__ g_T)
{
    __shared__ float smem[LL * DB + LL];
    const int tid = threadIdx.x;
    const int vt  = blockIdx.x * 256 + tid;

    g_T[vt] = 0.0f;   // exactly one element per thread

    for (int t = tid; t < LL * DB; t += 256) smem[t] = mu[t];
    if (tid < LL) smem[LL * DB + tid] = r[tid];
    __syncthreads();
    if (vt < NB * LL) {
        int m = vt / LL;
        int l = vt - m * LL;
        float kappa = 0.0f;
        #pragma unroll
        for (int d = 0; d < DB; ++d) {
            float diff = locs[m * DB + d] - smem[l * DB + d];
            kappa += diff * diff;
        }
        w_act[vt] = sigmoidf_fast(smem[LL * DB + l] - kappa);
    }
}

// K2: gemm (blocks 0-511) | repack (512-911) | out-init+beta (912-971).
// Repack/out-init are latency-bound and overlap the FMA-bound gemm blocks
// instead of serializing in their own dispatch.
__global__ __launch_bounds__(256) void k2_mix(
    const float* __restrict__ x,      // [B][NB]
    const float* __restrict__ w_act,  // [NB][LL]
    const float* __restrict__ alpha, const float* __restrict__ beta,
    const float* __restrict__ W1, const float* __restrict__ b1,
    const float* __restrict__ W2, const float* __restrict__ b2,
    const float* __restrict__ W3, const float* __restrict__ b3,
    const float* __restrict__ W4, const float* __restrict__ b4,
    float* __restrict__ g_T,          // [LL][B]
    float* __restrict__ blob, float* __restrict__ out)
{
    __shared__ float xs[64 * 125];    // dword bank stride 125 (odd->2-way, free)
    const int bidx = blockIdx.x;
    const int tid  = threadIdx.x;

    if (bidx < 512) {
        // g_T[l][b] += sum_m x[b][m] * w_act[m][l]
        // 32 b-tiles (64 b) x 16 m-splits (125 m). w_act through the SCALAR
        // pipe (wave-uniform base via readfirstlane -> s_load).
        int bb = bidx >> 4;   // 0..31
        int mq = bidx & 15;   // 0..15
        int i  = tid & 63;    // local b
        int wu = __builtin_amdgcn_readfirstlane(tid >> 6);  // l-group

        for (int t = tid; t < 64 * 125; t += 256) {
            int ii = t / 125;
            int jj = t - ii * 125;
            xs[t] = x[(bb * 64 + ii) * NB + mq * 125 + jj];
        }
        __syncthreads();

        const float* wrow = w_act + (mq * 125) * LL + wu * 10;
        const float* xrow = xs + i * 125;

        float acc[10];
        #pragma unroll
        for (int u = 0; u < 10; ++u) acc[u] = 0.0f;

        #pragma unroll 5
        for (int m = 0; m < 125; ++m) {
            float xv = xrow[m];
            #pragma unroll
            for (int u = 0; u < 10; ++u)
                acc[u] = fmaf(xv, wrow[m * LL + u], acc[u]);
        }

        #pragma unroll
        for (int u = 0; u < 10; ++u)
            atomicAdd(&g_T[(wu * 10 + u) * B_SZ + bb * 64 + i], acc[u]);
    } else if (bidx < 912) {
        // repack: one 64-lane wave per blob; blob id = (k*2+p)*40 + l
        int vt2 = (bidx - 512) * 256 + tid;   // 0..102399
        int bidb = vt2 >> 6;                  // 0..1599
        int t = vt2 & 63;
        int k = bidb / (PP * LL);
        int rem = bidb - k * (PP * LL);
        int p = rem / LL;
        int l = rem - p * LL;
        int iw = (k * LL + l) * PP + p;
        int n = t & 15, q = t >> 4;
        float* o = blob + (size_t)bidb * BLOB_F;
        float aact = sigmoidf_fast(alpha[l * KK + k]);
        if (t < 16) {
            o[t]      = W1[iw * 16 + t];
            o[16 + t] = b1[iw * 16 + t];
            o[32 + t] = b2[iw * 16 + t];
            o[48 + t] = (t < 8) ? b3[iw * 8 + t] : 0.0f;
            o[64 + t] = (t < 8) ? W4[iw * 8 + t] * aact : 0.0f;
        }
        _Float16* w2a = (_Float16*)(o + 80);
        #pragma unroll
        for (int j = 0; j < 4; ++j)
            w2a[t * 4 + j] = (_Float16)W2[iw * 256 + (4 * q + j) * 16 + n];
        _Float16* w3a = (_Float16*)(o + 208);
        #pragma unroll
        for (int j = 0; j < 4; ++j)
            w3a[t * 4 + j] = (n < 8) ? (_Float16)W3[iw * 128 + (4 * q + j) * 8 + n]
                                     : (_Float16)0.0f;
    } else {
        // out[b][k] = beta[k] + sum_{l,p} b4[k,l,p]*sigmoid(alpha[l,k])
        if (tid < KK) {
            int k = tid;
            float s = beta[k];
            for (int l = 0; l < LL; ++l) {
                float a = sigmoidf_fast(alpha[l * KK + k]);
                s += a * (b4[(k * LL + l) * PP + 0] + b4[(k * LL + l) * PP + 1]);
            }
            xs[tid] = s;
        }
        __syncthreads();
        int gid = (bidx - 912) * 256 + tid;    // 0..40959
        out[gid] = xs[gid % KK];
    }
}

// K3: NAM via chained MFMA. Hidden states feature-major [j][b]; MFMA C/D layout
// (col=lane&15=b, row=4q+reg=j) == next MFMA's B-operand layout -> no shuffles.
// Two k's per block (g prefetch reused, zero scheduling tail):
// bid = bb(16) | lc(4)<<4 | p(2)<<6 | kp(10)<<7 -> 1280 blocks = 5 blocks/CU.
__global__ __launch_bounds__(256) void k3_nam(
    const float* __restrict__ g_T,    // [LL][B]
    const float* __restrict__ blob,   // [K][P][LL][BLOB_F]
    float* __restrict__ out)          // [B][KK]
{
    __shared__ __align__(16) float sw[2][10 * BLOB_F];   // 26.9 KB: 5 blocks/CU

    int bid = blockIdx.x;
    int bb = bid & 15;
    int lc = (bid >> 4) & 3;
    int p  = (bid >> 6) & 1;
    int kp = bid >> 7;                // 0..9 -> k = 2*kp + kk
    int tid = threadIdx.x;

    const int wv = tid >> 6, lane = tid & 63;
    const int n = lane & 15, q = lane >> 4;
    int b0 = bb * 128 + wv * 32 + n;

    // prefetch g for all 10 l's before the staging barrier (latency hoist);
    // shared across both k's of this block.
    float gv0[10], gv1[10];
    #pragma unroll
    for (int u = 0; u < 10; ++u) {
        gv0[u] = g_T[(lc * 10 + u) * B_SZ + b0];
        gv1[u] = g_T[(lc * 10 + u) * B_SZ + b0 + 16];
    }

    {
        const float4* bl4 = (const float4*)blob;
        float4* sw4 = (float4*)sw;
        int base0 = (((2 * kp + 0) * PP + p) * LL + lc * 10) * (BLOB_F / 4);
        int base1 = (((2 * kp + 1) * PP + p) * LL + lc * 10) * (BLOB_F / 4);
        for (int t = tid; t < 10 * (BLOB_F / 4); t += 256) {
            sw4[t] = bl4[base0 + t];
            sw4[10 * (BLOB_F / 4) + t] = bl4[base1 + t];
        }
    }
    __syncthreads();

    #pragma unroll 1
    for (int kk = 0; kk < 2; ++kk) {
        float acc0 = 0.0f, acc1 = 0.0f;

        #pragma unroll 1
        for (int u = 0; u < 10; ++u) {
            const float* W = sw[kk] + u * BLOB_F;
            f32x4 w1q = *(const f32x4*)(W + q * 4);
            f32x4 b1q = *(const f32x4*)(W + 16 + q * 4);
            f32x4 b2q = *(const f32x4*)(W + 32 + q * 4);
            f32x4 b3q = *(const f32x4*)(W + 48 + q * 4);
            f32x4 w4q = *(const f32x4*)(W + 64 + q * 4);
            f16x4 w2a = *(const f16x4*)((const _Float16*)(W + 80) + lane * 4);
            f16x4 w3a = *(const f16x4*)((const _Float16*)(W + 208) + lane * 4);

            float g0 = gv0[u];
            float g1 = gv1[u];

            // layer 1: f32 fma pre-activations, RNE-pack to v2f16, packed elu.
            F16x4 hb0, hb1;
            hb0.h[0] = elu2(pack2(fmaf(g0, w1q[0], b1q[0]),
                                  fmaf(g0, w1q[1], b1q[1])));
            hb0.h[1] = elu2(pack2(fmaf(g0, w1q[2], b1q[2]),
                                  fmaf(g0, w1q[3], b1q[3])));
            hb1.h[0] = elu2(pack2(fmaf(g1, w1q[0], b1q[0]),
                                  fmaf(g1, w1q[1], b1q[1])));
            hb1.h[1] = elu2(pack2(fmaf(g1, w1q[2], b1q[2]),
                                  fmaf(g1, w1q[3], b1q[3])));

            // layer 2: D2 = W2T @ H1 + b2 (bias in C operand)
            f32x4 d20 = __builtin_amdgcn_mfma_f32_16x16x16f16(w2a, hb0.v, b2q, 0, 0, 0);
            f32x4 d21 = __builtin_amdgcn_mfma_f32_16x16x16f16(w2a, hb1.v, b2q, 0, 0, 0);

            F16x4 hc0, hc1;
            hc0.h[0] = elu2(pack2(d20[0], d20[1]));
            hc0.h[1] = elu2(pack2(d20[2], d20[3]));
            hc1.h[0] = elu2(pack2(d21[0], d21[1]));
            hc1.h[1] = elu2(pack2(d21[2], d21[3]));

            // layer 3: D3 = W3T @ H2 + b3 (bias in C operand; rows j'>=8 zero)
            f32x4 d30 = __builtin_amdgcn_mfma_f32_16x16x16f16(w3a, hc0.v, b3q, 0, 0, 0);
            f32x4 d31 = __builtin_amdgcn_mfma_f32_16x16x16f16(w3a, hc1.v, b3q, 0, 0, 0);

            // layer 4: acc += elu(h3) . W4f (f32 for accumulation accuracy;
            // q>=2 rows are zeroed -> contribute 0)
            #pragma unroll
            for (int rj = 0; rj < 4; ++rj) {
                acc0 = fmaf(eluf(d30[rj]), w4q[rj], acc0);
                acc1 = fmaf(eluf(d31[rj]), w4q[rj], acc1);
            }
        }

        acc0 += __shfl_xor(acc0, 16, 64);
        acc0 += __shfl_xor(acc0, 32, 64);
        acc1 += __shfl_xor(acc1, 16, 64);
        acc1 += __shfl_xor(acc1, 32, 64);
        if (lane < 16) {
            int k = 2 * kp + kk;
            atomicAdd(&out[b0 * KK + k], acc0);
            atomicAdd(&out[(b0 + 16) * KK + k], acc1);
        }
    }
}

extern "C" void kernel_launch(void* const* d_in, const int* in_sizes, int n_in,
                              void* d_out, int out_size, void* d_ws, size_t ws_size,
                              hipStream_t stream) {
    const float* x     = (const float*)d_in[0];
    const float* locs  = (const float*)d_in[1];
    const float* mu    = (const float*)d_in[2];
    const float* r     = (const float*)d_in[3];
    const float* alpha = (const float*)d_in[4];
    const float* beta  = (const float*)d_in[5];
    const float* W1    = (const float*)d_in[6];
    const float* b1    = (const float*)d_in[7];
    const float* W2    = (const float*)d_in[8];
    const float* b2    = (const float*)d_in[9];
    const float* W3    = (const float*)d_in[10];
    const float* b3    = (const float*)d_in[11];
    const float* W4    = (const float*)d_in[12];
    const float* b4    = (const float*)d_in[13];
    float* out = (float*)d_out;

    float* ws0   = (float*)d_ws;
    float* w_act = ws0;                              //  80000 f
    float* g_T   = w_act + NB * LL;                  //  81920 f
    float* blob  = g_T + LL * B_SZ;                  // 537600 f

    k1_wact<<<320, 256, 0, stream>>>(locs, mu, r, w_act, g_T);
    k2_mix<<<1072, 256, 0, stream>>>(x, w_act, alpha, beta,
                                     W1, b1, W2, b2, W3, b3, W4, b4,
                                     g_T, blob, out);
    k3_nam<<<1280, 256, 0, stream>>>(g_T, blob, out);
}

// Round 3
// 141.576 us; speedup vs baseline: 1.0312x; 1.0206x over previous
//
#include <hip/hip_runtime.h>

// Problem constants
#define B_SZ 2048
#define NB   2000
#define DB   30
#define KK   20
#define LL   40
#define PP   2

// Blob per (k,p,l) [stride 336 floats], order [k][p][l]:
//   0: W1[16] f32 | 16: b1[16] f32 | 32: b2[16] f32
//  48: b3p[16] f32 (j'>=8 -> 0) | 64: W4f[16] f32 (W4*sigmoid(alpha), j'>=8 -> 0)
//  80: W2A 256 f16 A-frag | 208: W3A 256 f16 A-frag (rows j'>=8 zero)
#define BLOB_F 336

typedef _Float16 f16x4 __attribute__((ext_vector_type(4)));
typedef _Float16 f16x2 __attribute__((ext_vector_type(2)));
typedef float    f32x4 __attribute__((ext_vector_type(4)));
typedef int      i32x2 __attribute__((ext_vector_type(2)));

union F16x4 { f16x4 v; f16x2 h[2]; };

__device__ __forceinline__ float sigmoidf_fast(float z) {
    return 1.0f / (1.0f + __expf(-z));
}
__device__ __forceinline__ float eluf(float x) {
    return x > 0.0f ? x : (__expf(x) - 1.0f);
}
// elu(x) = max(x, exp2(min(x,0)*log2e) - 1): exp(min(x,0))-1 >= x for x<=0
// (convexity), and = 0 <= x for x>0. Packed v2f16: v_pk_min/mul/add/max +
// 2x v_exp_f16 (op_sel).
__device__ __forceinline__ f16x2 elu2(f16x2 x) {
    const f16x2 z2  = {(_Float16)0.0f, (_Float16)0.0f};
    const f16x2 l2e = {(_Float16)1.4426950408889634f, (_Float16)1.4426950408889634f};
    const f16x2 m1  = {(_Float16)-1.0f, (_Float16)-1.0f};
    f16x2 e = __builtin_elementwise_exp2(__builtin_elementwise_min(x, z2) * l2e);
    return __builtin_elementwise_max(x, e + m1);
}
__device__ __forceinline__ f16x2 pack2(float a, float b) {
    f16x2 r = {(_Float16)a, (_Float16)b};   // RNE fptrunc
    return r;
}

// combine32(lo, hi): lanes 0-31 get lo (own), lanes 32-63 get hi of (lane-32).
// gfx950 v_permlane32_swap_b32 does this in ONE instr: new vdst = {lo[0:31],
// hi[0:31]}. Fallback: shfl_xor + cndmask.
__device__ __forceinline__ float combine32(float lo, float hi, int lane) {
#if __has_builtin(__builtin_amdgcn_permlane32_swap)
    i32x2 pr = __builtin_amdgcn_permlane32_swap(__float_as_int(lo),
                                                __float_as_int(hi),
                                                false, false);
    return __int_as_float(pr.x);
#else
    float t = __shfl_xor(hi, 32, 64);
    return (lane < 32) ? lo : t;
#endif
}

// K1: w_act only (+ g_T zero). 320 blocks * 256 = 81920 == LL*B_SZ exactly.
__global__ __launch_bounds__(256) void k1_wact(
    const float* __restrict__ locs, const float* __restrict__ mu,
    const float* __restrict__ r,
    float* __restrict__ w_act, float* __restrict__ g_T)
{
    __shared__ float smem[LL * DB + LL];
    const int tid = threadIdx.x;
    const int vt  = blockIdx.x * 256 + tid;

    g_T[vt] = 0.0f;   // exactly one element per thread

    for (int t = tid; t < LL * DB; t += 256) smem[t] = mu[t];
    if (tid < LL) smem[LL * DB + tid] = r[tid];
    __syncthreads();
    if (vt < NB * LL) {
        int m = vt / LL;
        int l = vt - m * LL;
        float kappa = 0.0f;
        #pragma unroll
        for (int d = 0; d < DB; ++d) {
            float diff = locs[m * DB + d] - smem[l * DB + d];
            kappa += diff * diff;
        }
        w_act[vt] = sigmoidf_fast(smem[LL * DB + l] - kappa);
    }
}

// K2: gemm (blocks 0-511) | repack (512-911) | out-init+beta (912-971).
__global__ __launch_bounds__(256) void k2_mix(
    const float* __restrict__ x,      // [B][NB]
    const float* __restrict__ w_act,  // [NB][LL]
    const float* __restrict__ alpha, const float* __restrict__ beta,
    const float* __restrict__ W1, const float* __restrict__ b1,
    const float* __restrict__ W2, const float* __restrict__ b2,
    const float* __restrict__ W3, const float* __restrict__ b3,
    const float* __restrict__ W4, const float* __restrict__ b4,
    float* __restrict__ g_T,          // [LL][B]
    float* __restrict__ blob, float* __restrict__ out)
{
    __shared__ float xs[64 * 125];    // dword bank stride 125 (odd->2-way, free)
    const int bidx = blockIdx.x;
    const int tid  = threadIdx.x;

    if (bidx < 512) {
        // g_T[l][b] += sum_m x[b][m] * w_act[m][l]
        int bb = bidx >> 4;   // 0..31
        int mq = bidx & 15;   // 0..15
        int i  = tid & 63;    // local b
        int wu = __builtin_amdgcn_readfirstlane(tid >> 6);  // l-group

        for (int t = tid; t < 64 * 125; t += 256) {
            int ii = t / 125;
            int jj = t - ii * 125;
            xs[t] = x[(bb * 64 + ii) * NB + mq * 125 + jj];
        }
        __syncthreads();

        const float* wrow = w_act + (mq * 125) * LL + wu * 10;
        const float* xrow = xs + i * 125;

        float acc[10];
        #pragma unroll
        for (int u = 0; u < 10; ++u) acc[u] = 0.0f;

        #pragma unroll 5
        for (int m = 0; m < 125; ++m) {
            float xv = xrow[m];
            #pragma unroll
            for (int u = 0; u < 10; ++u)
                acc[u] = fmaf(xv, wrow[m * LL + u], acc[u]);
        }

        #pragma unroll
        for (int u = 0; u < 10; ++u)
            atomicAdd(&g_T[(wu * 10 + u) * B_SZ + bb * 64 + i], acc[u]);
    } else if (bidx < 912) {
        // repack: one 64-lane wave per blob; blob id = (k*2+p)*40 + l
        int vt2 = (bidx - 512) * 256 + tid;   // 0..102399
        int bidb = vt2 >> 6;                  // 0..1599
        int t = vt2 & 63;
        int k = bidb / (PP * LL);
        int rem = bidb - k * (PP * LL);
        int p = rem / LL;
        int l = rem - p * LL;
        int iw = (k * LL + l) * PP + p;
        int n = t & 15, q = t >> 4;
        float* o = blob + (size_t)bidb * BLOB_F;
        float aact = sigmoidf_fast(alpha[l * KK + k]);
        if (t < 16) {
            o[t]      = W1[iw * 16 + t];
            o[16 + t] = b1[iw * 16 + t];
            o[32 + t] = b2[iw * 16 + t];
            o[48 + t] = (t < 8) ? b3[iw * 8 + t] : 0.0f;
            o[64 + t] = (t < 8) ? W4[iw * 8 + t] * aact : 0.0f;
        }
        _Float16* w2a = (_Float16*)(o + 80);
        #pragma unroll
        for (int j = 0; j < 4; ++j)
            w2a[t * 4 + j] = (_Float16)W2[iw * 256 + (4 * q + j) * 16 + n];
        _Float16* w3a = (_Float16*)(o + 208);
        #pragma unroll
        for (int j = 0; j < 4; ++j)
            w3a[t * 4 + j] = (n < 8) ? (_Float16)W3[iw * 128 + (4 * q + j) * 8 + n]
                                     : (_Float16)0.0f;
    } else {
        // out[b][k] = beta[k] + sum_{l,p} b4[k,l,p]*sigmoid(alpha[l,k])
        if (tid < KK) {
            int k = tid;
            float s = beta[k];
            for (int l = 0; l < LL; ++l) {
                float a = sigmoidf_fast(alpha[l * KK + k]);
                s += a * (b4[(k * LL + l) * PP + 0] + b4[(k * LL + l) * PP + 1]);
            }
            xs[tid] = s;
        }
        __syncthreads();
        int gid = (bidx - 912) * 256 + tid;    // 0..40959
        out[gid] = xs[gid % KK];
    }
}

// K3: NAM via chained MFMA. Hidden states feature-major [j][b]; MFMA C/D layout
// (col=lane&15=b, row=4q+reg=j) == next MFMA's B-operand layout -> no shuffles.
// Layer 4 is lane-consolidated: valid d3 rows (0-7) of BOTH b-halves are merged
// via permlane32_swap into one register -> 4 eluf instead of 8+8 (half of which
// were on w4==0 rows). Two k's per block: 1280 blocks = 5 blocks/CU.
__global__ __launch_bounds__(256) void k3_nam(
    const float* __restrict__ g_T,    // [LL][B]
    const float* __restrict__ blob,   // [K][P][LL][BLOB_F]
    float* __restrict__ out)          // [B][KK]
{
    __shared__ __align__(16) float sw[2][10 * BLOB_F];   // 26.9 KB: 5 blocks/CU

    int bid = blockIdx.x;
    int bb = bid & 15;
    int lc = (bid >> 4) & 3;
    int p  = (bid >> 6) & 1;
    int kp = bid >> 7;                // 0..9 -> k = 2*kp + kk
    int tid = threadIdx.x;

    const int wv = tid >> 6, lane = tid & 63;
    const int n = lane & 15, q = lane >> 4;
    int b0 = bb * 128 + wv * 32 + n;

    // prefetch g for all 10 l's before the staging barrier (latency hoist);
    // shared across both k's of this block.
    float gv0[10], gv1[10];
    #pragma unroll
    for (int u = 0; u < 10; ++u) {
        gv0[u] = g_T[(lc * 10 + u) * B_SZ + b0];
        gv1[u] = g_T[(lc * 10 + u) * B_SZ + b0 + 16];
    }

    {
        const float4* bl4 = (const float4*)blob;
        float4* sw4 = (float4*)sw;
        int base0 = (((2 * kp + 0) * PP + p) * LL + lc * 10) * (BLOB_F / 4);
        int base1 = (((2 * kp + 1) * PP + p) * LL + lc * 10) * (BLOB_F / 4);
        for (int t = tid; t < 10 * (BLOB_F / 4); t += 256) {
            sw4[t] = bl4[base0 + t];
            sw4[10 * (BLOB_F / 4) + t] = bl4[base1 + t];
        }
    }
    __syncthreads();

    #pragma unroll 1
    for (int kk = 0; kk < 2; ++kk) {
        float acc = 0.0f;

        #pragma unroll 1
        for (int u = 0; u < 10; ++u) {
            const float* W = sw[kk] + u * BLOB_F;
            f32x4 w1q = *(const f32x4*)(W + q * 4);
            f32x4 b1q = *(const f32x4*)(W + 16 + q * 4);
            f32x4 b2q = *(const f32x4*)(W + 32 + q * 4);
            f32x4 b3q = *(const f32x4*)(W + 48 + q * 4);
            // w4 indexed by q&1: lanes >=32 process the SAME valid rows 0..7
            // (they receive d31's lanes 0..31 via permlane below).
            f32x4 w4h = *(const f32x4*)(W + 64 + (q & 1) * 4);
            f16x4 w2a = *(const f16x4*)((const _Float16*)(W + 80) + lane * 4);
            f16x4 w3a = *(const f16x4*)((const _Float16*)(W + 208) + lane * 4);

            float g0 = gv0[u];
            float g1 = gv1[u];

            // layer 1: f32 fma pre-activations, RNE-pack to v2f16, packed elu.
            F16x4 hb0, hb1;
            hb0.h[0] = elu2(pack2(fmaf(g0, w1q[0], b1q[0]),
                                  fmaf(g0, w1q[1], b1q[1])));
            hb0.h[1] = elu2(pack2(fmaf(g0, w1q[2], b1q[2]),
                                  fmaf(g0, w1q[3], b1q[3])));
            hb1.h[0] = elu2(pack2(fmaf(g1, w1q[0], b1q[0]),
                                  fmaf(g1, w1q[1], b1q[1])));
            hb1.h[1] = elu2(pack2(fmaf(g1, w1q[2], b1q[2]),
                                  fmaf(g1, w1q[3], b1q[3])));

            // layer 2: D2 = W2T @ H1 + b2 (bias in C operand)
            f32x4 d20 = __builtin_amdgcn_mfma_f32_16x16x16f16(w2a, hb0.v, b2q, 0, 0, 0);
            f32x4 d21 = __builtin_amdgcn_mfma_f32_16x16x16f16(w2a, hb1.v, b2q, 0, 0, 0);

            F16x4 hc0, hc1;
            hc0.h[0] = elu2(pack2(d20[0], d20[1]));
            hc0.h[1] = elu2(pack2(d20[2], d20[3]));
            hc1.h[0] = elu2(pack2(d21[0], d21[1]));
            hc1.h[1] = elu2(pack2(d21[2], d21[3]));

            // layer 3: D3 = W3T @ H2 + b3 (bias in C operand; rows j'>=8 zero)
            f32x4 d30 = __builtin_amdgcn_mfma_f32_16x16x16f16(w3a, hc0.v, b3q, 0, 0, 0);
            f32x4 d31 = __builtin_amdgcn_mfma_f32_16x16x16f16(w3a, hc1.v, b3q, 0, 0, 0);

            // layer 4: merge valid rows of both b-halves (lanes<32: d30 rows
            // 0-7; lanes>=32: d31 rows 0-7) -> 4 eluf covers what took 8+8.
            #pragma unroll
            for (int rj = 0; rj < 4; ++rj) {
                float dv = combine32(d30[rj], d31[rj], lane);
                acc = fmaf(eluf(dv), w4h[rj], acc);
            }
        }

        // reduce over the two q'-groups within each half, then write per half.
        acc += __shfl_xor(acc, 16, 64);
        if ((lane & 31) < 16) {
            int k = 2 * kp + kk;
            int bout = b0 + ((lane & 32) ? 16 : 0);
            atomicAdd(&out[bout * KK + k], acc);
        }
    }
}

extern "C" void kernel_launch(void* const* d_in, const int* in_sizes, int n_in,
                              void* d_out, int out_size, void* d_ws, size_t ws_size,
                              hipStream_t stream) {
    const float* x     = (const float*)d_in[0];
    const float* locs  = (const float*)d_in[1];
    const float* mu    = (const float*)d_in[2];
    const float* r     = (const float*)d_in[3];
    const float* alpha = (const float*)d_in[4];
    const float* beta  = (const float*)d_in[5];
    const float* W1    = (const float*)d_in[6];
    const float* b1    = (const float*)d_in[7];
    const float* W2    = (const float*)d_in[8];
    const float* b2    = (const float*)d_in[9];
    const float* W3    = (const float*)d_in[10];
    const float* b3    = (const float*)d_in[11];
    const float* W4    = (const float*)d_in[12];
    const float* b4    = (const float*)d_in[13];
    float* out = (float*)d_out;

    float* ws0   = (float*)d_ws;
    float* w_act = ws0;                              //  80000 f
    float* g_T   = w_act + NB * LL;                  //  81920 f
    float* blob  = g_T + LL * B_SZ;                  // 537600 f

    k1_wact<<<320, 256, 0, stream>>>(locs, mu, r, w_act, g_T);
    k2_mix<<<1072, 256, 0, stream>>>(x, w_act, alpha, beta,
                                     W1, b1, W2, b2, W3, b3, W4, b4,
                                     g_T, blob, out);
    k3_nam<<<1280, 256, 0, stream>>>(g_T, blob, out);
}

// Round 5
// 139.971 us; speedup vs baseline: 1.0430x; 1.0115x over previous
//
#include <hip/hip_runtime.h>

// Problem constants
#define B_SZ 2048
#define NB   2000
#define DB   30
#define KK   20
#define LL   40
#define PP   2

// Blob per (k,p,l) [stride 336 floats], order [k][p][l]:
//   0: W1[16] f32 | 16: b1[16] f32 | 32: b2[16] f32
//  48: b3p[16] f32 (j'>=8 -> 0) | 64: W4f[16] f32 (W4*sigmoid(alpha), j'>=8 -> 0)
//  80: W2A 256 f16 A-frag | 208: W3A 256 f16 A-frag (rows j'>=8 zero)
#define BLOB_F 336

typedef _Float16 f16x4 __attribute__((ext_vector_type(4)));
typedef _Float16 f16x2 __attribute__((ext_vector_type(2)));
typedef float    f32x4 __attribute__((ext_vector_type(4)));
typedef int      i32x2 __attribute__((ext_vector_type(2)));

union F16x4 { f16x4 v; f16x2 h[2]; };

__device__ __forceinline__ float sigmoidf_fast(float z) {
    return 1.0f / (1.0f + __expf(-z));
}
__device__ __forceinline__ float eluf(float x) {
    return x > 0.0f ? x : (__expf(x) - 1.0f);
}
// elu(x) = max(x, exp2(min(x,0)*log2e) - 1): exp(min(x,0))-1 >= x for x<=0
// (convexity), and = 0 <= x for x>0. Packed v2f16: v_pk_min/mul/add/max +
// 2x v_exp_f16 (op_sel).
__device__ __forceinline__ f16x2 elu2(f16x2 x) {
    const f16x2 z2  = {(_Float16)0.0f, (_Float16)0.0f};
    const f16x2 l2e = {(_Float16)1.4426950408889634f, (_Float16)1.4426950408889634f};
    const f16x2 m1  = {(_Float16)-1.0f, (_Float16)-1.0f};
    f16x2 e = __builtin_elementwise_exp2(__builtin_elementwise_min(x, z2) * l2e);
    return __builtin_elementwise_max(x, e + m1);
}
// Single-instruction packed f32->f16 conversion (v_cvt_pkrtz_f16_f32, RTZ).
// RTZ vs RNE is <=1 f16 ulp -- same scale as the f16 rounding these values
// already undergo before the MFMA. Builtin returns __fp16x2; bit-identical
// layout to f16x2, so reinterpret.
__device__ __forceinline__ f16x2 pack2(float a, float b) {
#if __has_builtin(__builtin_amdgcn_cvt_pkrtz)
    return __builtin_bit_cast(f16x2, __builtin_amdgcn_cvt_pkrtz(a, b));
#else
    f16x2 r = {(_Float16)a, (_Float16)b};   // RNE fallback
    return r;
#endif
}

// combine32(lo, hi): lanes 0-31 get lo (own), lanes 32-63 get hi of (lane-32).
// gfx950 v_permlane32_swap_b32 does this in ONE instr: new vdst = {lo[0:31],
// hi[0:31]}. Fallback: shfl_xor + cndmask.
__device__ __forceinline__ float combine32(float lo, float hi, int lane) {
#if __has_builtin(__builtin_amdgcn_permlane32_swap)
    i32x2 pr = __builtin_amdgcn_permlane32_swap(__float_as_int(lo),
                                                __float_as_int(hi),
                                                false, false);
    return __int_as_float(pr.x);
#else
    float t = __shfl_xor(hi, 32, 64);
    return (lane < 32) ? lo : t;
#endif
}

// K1: w_act only (+ g_T zero). 320 blocks * 256 = 81920 == LL*B_SZ exactly.
__global__ __launch_bounds__(256) void k1_wact(
    const float* __restrict__ locs, const float* __restrict__ mu,
    const float* __restrict__ r,
    float* __restrict__ w_act, float* __restrict__ g_T)
{
    __shared__ float smem[LL * DB + LL];
    const int tid = threadIdx.x;
    const int vt  = blockIdx.x * 256 + tid;

    g_T[vt] = 0.0f;   // exactly one element per thread

    for (int t = tid; t < LL * DB; t += 256) smem[t] = mu[t];
    if (tid < LL) smem[LL * DB + tid] = r[tid];
    __syncthreads();
    if (vt < NB * LL) {
        int m = vt / LL;
        int l = vt - m * LL;
        float kappa = 0.0f;
        #pragma unroll
        for (int d = 0; d < DB; ++d) {
            float diff = locs[m * DB + d] - smem[l * DB + d];
            kappa += diff * diff;
        }
        w_act[vt] = sigmoidf_fast(smem[LL * DB + l] - kappa);
    }
}

// K2: gemm (blocks 0-511) | repack (512-911) | out-init+beta (912-971).
__global__ __launch_bounds__(256) void k2_mix(
    const float* __restrict__ x,      // [B][NB]
    const float* __restrict__ w_act,  // [NB][LL]
    const float* __restrict__ alpha, const float* __restrict__ beta,
    const float* __restrict__ W1, const float* __restrict__ b1,
    const float* __restrict__ W2, const float* __restrict__ b2,
    const float* __restrict__ W3, const float* __restrict__ b3,
    const float* __restrict__ W4, const float* __restrict__ b4,
    float* __restrict__ g_T,          // [LL][B]
    float* __restrict__ blob, float* __restrict__ out)
{
    __shared__ float xs[64 * 125];    // dword bank stride 125 (odd->2-way, free)
    const int bidx = blockIdx.x;
    const int tid  = threadIdx.x;

    if (bidx < 512) {
        // g_T[l][b] += sum_m x[b][m] * w_act[m][l]
        int bb = bidx >> 4;   // 0..31
        int mq = bidx & 15;   // 0..15
        int i  = tid & 63;    // local b
        int wu = __builtin_amdgcn_readfirstlane(tid >> 6);  // l-group

        for (int t = tid; t < 64 * 125; t += 256) {
            int ii = t / 125;
            int jj = t - ii * 125;
            xs[t] = x[(bb * 64 + ii) * NB + mq * 125 + jj];
        }
        __syncthreads();

        const float* wrow = w_act + (mq * 125) * LL + wu * 10;
        const float* xrow = xs + i * 125;

        float acc[10];
        #pragma unroll
        for (int u = 0; u < 10; ++u) acc[u] = 0.0f;

        #pragma unroll 5
        for (int m = 0; m < 125; ++m) {
            float xv = xrow[m];
            #pragma unroll
            for (int u = 0; u < 10; ++u)
                acc[u] = fmaf(xv, wrow[m * LL + u], acc[u]);
        }

        #pragma unroll
        for (int u = 0; u < 10; ++u)
            atomicAdd(&g_T[(wu * 10 + u) * B_SZ + bb * 64 + i], acc[u]);
    } else if (bidx < 912) {
        // repack: one 64-lane wave per blob; blob id = (k*2+p)*40 + l
        int vt2 = (bidx - 512) * 256 + tid;   // 0..102399
        int bidb = vt2 >> 6;                  // 0..1599
        int t = vt2 & 63;
        int k = bidb / (PP * LL);
        int rem = bidb - k * (PP * LL);
        int p = rem / LL;
        int l = rem - p * LL;
        int iw = (k * LL + l) * PP + p;
        int n = t & 15, q = t >> 4;
        float* o = blob + (size_t)bidb * BLOB_F;
        float aact = sigmoidf_fast(alpha[l * KK + k]);
        if (t < 16) {
            o[t]      = W1[iw * 16 + t];
            o[16 + t] = b1[iw * 16 + t];
            o[32 + t] = b2[iw * 16 + t];
            o[48 + t] = (t < 8) ? b3[iw * 8 + t] : 0.0f;
            o[64 + t] = (t < 8) ? W4[iw * 8 + t] * aact : 0.0f;
        }
        _Float16* w2a = (_Float16*)(o + 80);
        #pragma unroll
        for (int j = 0; j < 4; ++j)
            w2a[t * 4 + j] = (_Float16)W2[iw * 256 + (4 * q + j) * 16 + n];
        _Float16* w3a = (_Float16*)(o + 208);
        #pragma unroll
        for (int j = 0; j < 4; ++j)
            w3a[t * 4 + j] = (n < 8) ? (_Float16)W3[iw * 128 + (4 * q + j) * 8 + n]
                                     : (_Float16)0.0f;
    } else {
        // out[b][k] = beta[k] + sum_{l,p} b4[k,l,p]*sigmoid(alpha[l,k])
        if (tid < KK) {
            int k = tid;
            float s = beta[k];
            for (int l = 0; l < LL; ++l) {
                float a = sigmoidf_fast(alpha[l * KK + k]);
                s += a * (b4[(k * LL + l) * PP + 0] + b4[(k * LL + l) * PP + 1]);
            }
            xs[tid] = s;
        }
        __syncthreads();
        int gid = (bidx - 912) * 256 + tid;    // 0..40959
        out[gid] = xs[gid % KK];
    }
}

// K3: NAM via chained MFMA. Hidden states feature-major [j][b]; MFMA C/D layout
// (col=lane&15=b, row=4q+reg=j) == next MFMA's B-operand layout -> no shuffles.
// Layer 4 lane-consolidated via permlane32_swap (valid rows of both b-halves in
// one register) and evaluated with the packed f16 elu. All f32->f16 packs use
// v_cvt_pkrtz (1 instr). Two k's per block: 1280 blocks = 5 blocks/CU.
__global__ __launch_bounds__(256) void k3_nam(
    const float* __restrict__ g_T,    // [LL][B]
    const float* __restrict__ blob,   // [K][P][LL][BLOB_F]
    float* __restrict__ out)          // [B][KK]
{
    __shared__ __align__(16) float sw[2][10 * BLOB_F];   // 26.9 KB: 5 blocks/CU

    int bid = blockIdx.x;
    int bb = bid & 15;
    int lc = (bid >> 4) & 3;
    int p  = (bid >> 6) & 1;
    int kp = bid >> 7;                // 0..9 -> k = 2*kp + kk
    int tid = threadIdx.x;

    const int wv = tid >> 6, lane = tid & 63;
    const int n = lane & 15, q = lane >> 4;
    int b0 = bb * 128 + wv * 32 + n;

    // prefetch g for all 10 l's before the staging barrier (latency hoist);
    // shared across both k's of this block.
    float gv0[10], gv1[10];
    #pragma unroll
    for (int u = 0; u < 10; ++u) {
        gv0[u] = g_T[(lc * 10 + u) * B_SZ + b0];
        gv1[u] = g_T[(lc * 10 + u) * B_SZ + b0 + 16];
    }

    {
        const float4* bl4 = (const float4*)blob;
        float4* sw4 = (float4*)sw;
        int base0 = (((2 * kp + 0) * PP + p) * LL + lc * 10) * (BLOB_F / 4);
        int base1 = (((2 * kp + 1) * PP + p) * LL + lc * 10) * (BLOB_F / 4);
        for (int t = tid; t < 10 * (BLOB_F / 4); t += 256) {
            sw4[t] = bl4[base0 + t];
            sw4[10 * (BLOB_F / 4) + t] = bl4[base1 + t];
        }
    }
    __syncthreads();

    #pragma unroll 1
    for (int kk = 0; kk < 2; ++kk) {
        float acc = 0.0f;

        #pragma unroll 1
        for (int u = 0; u < 10; ++u) {
            const float* W = sw[kk] + u * BLOB_F;
            f32x4 w1q = *(const f32x4*)(W + q * 4);
            f32x4 b1q = *(const f32x4*)(W + 16 + q * 4);
            f32x4 b2q = *(const f32x4*)(W + 32 + q * 4);
            f32x4 b3q = *(const f32x4*)(W + 48 + q * 4);
            // w4 indexed by q&1: lanes >=32 process the SAME valid rows 0..7
            // (they receive d31's lanes 0..31 via permlane below).
            f32x4 w4h = *(const f32x4*)(W + 64 + (q & 1) * 4);
            f16x4 w2a = *(const f16x4*)((const _Float16*)(W + 80) + lane * 4);
            f16x4 w3a = *(const f16x4*)((const _Float16*)(W + 208) + lane * 4);

            float g0 = gv0[u];
            float g1 = gv1[u];

            // layer 1: f32 fma pre-activations, pkrtz-pack to v2f16, packed elu.
            F16x4 hb0, hb1;
            hb0.h[0] = elu2(pack2(fmaf(g0, w1q[0], b1q[0]),
                                  fmaf(g0, w1q[1], b1q[1])));
            hb0.h[1] = elu2(pack2(fmaf(g0, w1q[2], b1q[2]),
                                  fmaf(g0, w1q[3], b1q[3])));
            hb1.h[0] = elu2(pack2(fmaf(g1, w1q[0], b1q[0]),
                                  fmaf(g1, w1q[1], b1q[1])));
            hb1.h[1] = elu2(pack2(fmaf(g1, w1q[2], b1q[2]),
                                  fmaf(g1, w1q[3], b1q[3])));

            // layer 2: D2 = W2T @ H1 + b2 (bias in C operand)
            f32x4 d20 = __builtin_amdgcn_mfma_f32_16x16x16f16(w2a, hb0.v, b2q, 0, 0, 0);
            f32x4 d21 = __builtin_amdgcn_mfma_f32_16x16x16f16(w2a, hb1.v, b2q, 0, 0, 0);

            F16x4 hc0, hc1;
            hc0.h[0] = elu2(pack2(d20[0], d20[1]));
            hc0.h[1] = elu2(pack2(d20[2], d20[3]));
            hc1.h[0] = elu2(pack2(d21[0], d21[1]));
            hc1.h[1] = elu2(pack2(d21[2], d21[3]));

            // layer 3: D3 = W3T @ H2 + b3 (bias in C operand; rows j'>=8 zero)
            f32x4 d30 = __builtin_amdgcn_mfma_f32_16x16x16f16(w3a, hc0.v, b3q, 0, 0, 0);
            f32x4 d31 = __builtin_amdgcn_mfma_f32_16x16x16f16(w3a, hc1.v, b3q, 0, 0, 0);

            // layer 4: merge valid rows of both b-halves (lanes<32: d30 rows
            // 0-7; lanes>=32: d31 rows 0-7), packed f16 elu, f32 accumulate.
            float dv0 = combine32(d30[0], d31[0], lane);
            float dv1 = combine32(d30[1], d31[1], lane);
            float dv2 = combine32(d30[2], d31[2], lane);
            float dv3 = combine32(d30[3], d31[3], lane);
            f16x2 e01 = elu2(pack2(dv0, dv1));
            f16x2 e23 = elu2(pack2(dv2, dv3));
            acc = fmaf((float)e01[0], w4h[0], acc);
            acc = fmaf((float)e01[1], w4h[1], acc);
            acc = fmaf((float)e23[0], w4h[2], acc);
            acc = fmaf((float)e23[1], w4h[3], acc);
        }

        // reduce over the two q'-groups within each half, then write per half.
        acc += __shfl_xor(acc, 16, 64);
        if ((lane & 31) < 16) {
            int k = 2 * kp + kk;
            int bout = b0 + ((lane & 32) ? 16 : 0);
            atomicAdd(&out[bout * KK + k], acc);
        }
    }
}

extern "C" void kernel_launch(void* const* d_in, const int* in_sizes, int n_in,
                              void* d_out, int out_size, void* d_ws, size_t ws_size,
                              hipStream_t stream) {
    const float* x     = (const float*)d_in[0];
    const float* locs  = (const float*)d_in[1];
    const float* mu    = (const float*)d_in[2];
    const float* r     = (const float*)d_in[3];
    const float* alpha = (const float*)d_in[4];
    const float* beta  = (const float*)d_in[5];
    const float* W1    = (const float*)d_in[6];
    const float* b1    = (const float*)d_in[7];
    const float* W2    = (const float*)d_in[8];
    const float* b2    = (const float*)d_in[9];
    const float* W3    = (const float*)d_in[10];
    const float* b3    = (const float*)d_in[11];
    const float* W4    = (const float*)d_in[12];
    const float* b4    = (const float*)d_in[13];
    float* out = (float*)d_out;

    float* ws0   = (float*)d_ws;
    float* w_act = ws0;                              //  80000 f
    float* g_T   = w_act + NB * LL;                  //  81920 f
    float* blob  = g_T + LL * B_SZ;                  // 537600 f

    k1_wact<<<320, 256, 0, stream>>>(locs, mu, r, w_act, g_T);
    k2_mix<<<1072, 256, 0, stream>>>(x, w_act, alpha, beta,
                                     W1, b1, W2, b2, W3, b3, W4, b4,
                                     g_T, blob, out);
    k3_nam<<<1280, 256, 0, stream>>>(g_T, blob, out);
}